// Round 6
// baseline (134.771 us; speedup 1.0000x reference)
//
#include <hip/hip_runtime.h>
#include <hip/hip_bf16.h>

#define Bsz 4
#define Lsz 2048
#define Hsz 8

typedef __attribute__((ext_vector_type(8))) short bf16x8;
typedef __attribute__((ext_vector_type(4))) short bf16x4;
typedef __attribute__((ext_vector_type(4))) float f32x4;

__device__ __forceinline__ short f2bs(float f) {   // RNE, prep only
    union { float f; unsigned u; } v; v.f = f;
    unsigned r = v.u + 0x7FFFu + ((v.u >> 16) & 1u);
    return (short)(r >> 16);
}
__device__ __forceinline__ short f2bs_rh(float f) { // round-half-up, 2 ops
    return (short)((__float_as_uint(f) + 0x8000u) >> 16);
}

// async global->LDS, 16B per lane; LDS dest is wave-uniform base + lane*16
__device__ __forceinline__ void stage16(const short* g, short* l) {
    __builtin_amdgcn_global_load_lds(
        (const __attribute__((address_space(1))) unsigned int*)g,
        (__attribute__((address_space(3))) unsigned int*)l,
        16, 0, 0);
}

// ---------------- fused pre-pass: K and V -> bf16 MFMA fragments ----------------
// Per (bh, 64-key tile): 8 chunks x 1024 B, frag position = lane (conflict-free
// lane-linear LDS reads in main).
// K chunk c=nt*2+eh, lane(quad,ln): K[k0+nt*16+ln][eh*32+quad*8+j]  (A-op 16x16x32)
// V chunk c=m16*2+ntp, lane: 16B = [frag(nt=2ntp) | frag(nt=2ntp+1)], each
//   frag = V[k0+nt*16+quad*4+j][m16*16+ln] j=0..3                   (A-op 16x16x16)
__global__ __launch_bounds__(256) void prep_kv(
    const float* __restrict__ ksrc, const float* __restrict__ vsrc,
    short* __restrict__ Kf, short* __restrict__ Vf)
{
    __shared__ float Tl[64][65];
    const int raw = blockIdx.x;
    const int tid = threadIdx.x;
    const bool isK = raw < Bsz*Hsz*32;
    const int bid = isK ? raw : raw - Bsz*Hsz*32;
    const int tl = bid & 31, bh = bid >> 5;
    const int b = bh >> 3, h = bh & 7;

    // coalesced stage of the 64x64 fp32 tile
    const int row = tid >> 2, c0 = (tid & 3) * 16;
    const float* src = (isK ? ksrc : vsrc)
                     + (((size_t)b*Lsz + tl*64 + row)*Hsz + h)*64 + c0;
    *(float4*)&Tl[row][c0]      = *(const float4*)(src);
    *(float4*)&Tl[row][c0 + 4]  = *(const float4*)(src + 4);
    *(float4*)&Tl[row][c0 + 8]  = *(const float4*)(src + 8);
    *(float4*)&Tl[row][c0 + 12] = *(const float4*)(src + 12);
    __syncthreads();

    const int lane = tid & 63, ln = lane & 15, quad = lane >> 4;
    if (isK) {
        short* dst = Kf + (size_t)bid * 4096;
        #pragma unroll
        for (int cc = 0; cc < 2; ++cc) {
            const int c  = (tid >> 6)*2 + cc;
            const int nt = c >> 1, eh = c & 1;
            const float* rp = &Tl[nt*16 + ln][eh*32 + quad*8];
            bf16x8 o = {f2bs(rp[0]),f2bs(rp[1]),f2bs(rp[2]),f2bs(rp[3]),
                        f2bs(rp[4]),f2bs(rp[5]),f2bs(rp[6]),f2bs(rp[7])};
            *(bf16x8*)(dst + c*512 + lane*8) = o;
        }
    } else {
        short* dst = Vf + (size_t)bid * 4096;
        #pragma unroll
        for (int cc = 0; cc < 2; ++cc) {
            const int cp  = (tid >> 6)*2 + cc;
            const int m16 = cp >> 1, nt0 = (cp & 1)*2;
            const int d   = m16*16 + ln;
            const int s0  = nt0*16 + quad*4;
            bf16x8 o = {f2bs(Tl[s0+0][d]),  f2bs(Tl[s0+1][d]),
                        f2bs(Tl[s0+2][d]),  f2bs(Tl[s0+3][d]),
                        f2bs(Tl[s0+16][d]), f2bs(Tl[s0+17][d]),
                        f2bs(Tl[s0+18][d]), f2bs(Tl[s0+19][d])};
            *(bf16x8*)(dst + cp*512 + lane*8) = o;
        }
    }
}

// ---------------- main: S^T flash attention, zero-shuffle P->PV ----------------
// 256 thr = 4 waves; wave owns 32 q-rows (2 halves of 16); block = 128 q-rows.
// S^T = mfma_16x16x32(kf, qf): C-layout key=quad*4+r, q=ln  ==  B-operand
// layout of mfma_16x16x16 -> P^T feeds O^T = V^T * P^T directly from regs.
// No-max softmax (|logit*log2e*scale*tau| <= ~13.5, l <= 2.4e7: fp32-safe).
__global__ __launch_bounds__(256, 2) void dsattn_main(
    const float* __restrict__ q,
    const short* __restrict__ Kf,
    const short* __restrict__ Vf,
    const float* __restrict__ tau,
    const float* __restrict__ delta,
    float* __restrict__ out)
{
    __shared__ __align__(16) short Kb[2][4096];   // 16 KB dbuf
    __shared__ __align__(16) short Vb[2][4096];   // 16 KB dbuf
    __shared__ float dls[Lsz];                    //  8 KB c2*delta[b][:]

    const int tid  = threadIdx.x;
    const int wv   = tid >> 6;
    const int lane = tid & 63;
    const int ln   = lane & 15;
    const int quad = lane >> 4;

    const int bh = blockIdx.x;
    const int b  = bh >> 3, h = bh & 7;
    // co-resident pair (j, j+8): qt pair (j, 15-j) -> equal tiles per CU
    const int j  = blockIdx.y;
    const int qt = (j < 8) ? j : 23 - j;
    const int q0 = qt * 128;
    const int T  = 2*qt + 2;
    const int Tw = (wv < 2) ? T - 1 : T;    // waves 0,1 don't need the last tile

    const float c2  = 0.125f * 1.44269504f;   // scale * log2(e)
    const float st2 = c2 * tau[b];

    const short* kt = Kf + (size_t)bh * (32*4096);
    const short* vt = Vf + (size_t)bh * (32*4096);

    // stage c2*delta (256 thr x 8 floats)
    {
        const float* dsrc = delta + (size_t)b*Lsz + tid*8;
        float4 a = *(const float4*)(dsrc);
        float4 c = *(const float4*)(dsrc + 4);
        a.x*=c2; a.y*=c2; a.z*=c2; a.w*=c2;
        c.x*=c2; c.y*=c2; c.z*=c2; c.w*=c2;
        *(float4*)&dls[tid*8]     = a;
        *(float4*)&dls[tid*8 + 4] = c;
    }

    // stage tile 0 (16 chunks of 1KB; wave wv does chunks wv*4..+3)
    #pragma unroll
    for (int u = 0; u < 4; ++u) {
        const int c = wv*4 + u;
        const short* g = ((c < 8) ? kt : vt) + (c & 7)*512 + lane*8;
        short* l = ((c < 8) ? &Kb[0][0] : &Vb[0][0]) + (c & 7)*512;
        stage16(g, l);
    }

    // Q fragments for both 16-row halves (B-operand of 16x16x32)
    bf16x8 qf[2][2];
    #pragma unroll
    for (int hh = 0; hh < 2; ++hh) {
        const float* qrow = q + (((size_t)b*Lsz + q0 + wv*32 + hh*16 + ln)*Hsz + h)*64;
        float4 a0 = *(const float4*)(qrow + quad*8);
        float4 a1 = *(const float4*)(qrow + quad*8 + 4);
        float4 b0 = *(const float4*)(qrow + 32 + quad*8);
        float4 b1 = *(const float4*)(qrow + 32 + quad*8 + 4);
        qf[hh][0] = (bf16x8){f2bs(a0.x),f2bs(a0.y),f2bs(a0.z),f2bs(a0.w),
                             f2bs(a1.x),f2bs(a1.y),f2bs(a1.z),f2bs(a1.w)};
        qf[hh][1] = (bf16x8){f2bs(b0.x),f2bs(b0.y),f2bs(b0.z),f2bs(b0.w),
                             f2bs(b1.x),f2bs(b1.y),f2bs(b1.z),f2bs(b1.w)};
    }

    f32x4 oacc[2][4];
    #pragma unroll
    for (int hh = 0; hh < 2; ++hh)
        #pragma unroll
        for (int m = 0; m < 4; ++m) oacc[hh][m] = (f32x4){0.f,0.f,0.f,0.f};
    float l_acc[2] = {0.f, 0.f};

    __syncthreads();   // tile 0 + dls staged (barrier drains vmcnt)

    for (int t = 0; t < T; ++t) {
        const int cur = t & 1;
        if (t + 1 < T) {                       // stream tile t+1 into other buffer
            const int nb = cur ^ 1;
            #pragma unroll
            for (int u = 0; u < 4; ++u) {
                const int c = wv*4 + u;
                const short* g = ((c < 8) ? kt : vt)
                               + (size_t)(t+1)*4096 + (c & 7)*512 + lane*8;
                short* l = ((c < 8) ? &Kb[nb][0] : &Vb[nb][0]) + (c & 7)*512;
                stage16(g, l);
            }
        }

        if (t < Tw) {
            const short* Kc = &Kb[cur][0];
            const short* Vc = &Vb[cur][0];
            const int k0 = t*64;

            // ---- S^T = K Q^T : lane holds [key=k0+nt*16+quad*4+r][q=base+ln] ----
            f32x4 sacc[2][4];
            #pragma unroll
            for (int nt = 0; nt < 4; ++nt) {
                bf16x8 kf0 = *(const bf16x8*)(Kc + (nt*2+0)*512 + lane*8);
                bf16x8 kf1 = *(const bf16x8*)(Kc + (nt*2+1)*512 + lane*8);
                #pragma unroll
                for (int hh = 0; hh < 2; ++hh) {
                    f32x4 z = (f32x4){0.f,0.f,0.f,0.f};
                    z = __builtin_amdgcn_mfma_f32_16x16x32_bf16(kf0, qf[hh][0], z, 0,0,0);
                    sacc[hh][nt] = __builtin_amdgcn_mfma_f32_16x16x32_bf16(kf1, qf[hh][1], z, 0,0,0);
                }
            }

            // ---- delta (key-indexed, broadcast b128 reads) ----
            f32x4 dlv[4];
            #pragma unroll
            for (int nt = 0; nt < 4; ++nt)
                dlv[nt] = *(const f32x4*)&dls[k0 + nt*16 + quad*4];

            // ---- mask, exp2, pack P^T (stays in registers) ----
            bf16x4 pT[2][4];
            #pragma unroll
            for (int hh = 0; hh < 2; ++hh) {
                const int qmin = q0 + wv*32 + hh*16;
                if (k0 + 63 > qmin) {          // tile crosses diagonal for this half
                    const int qrow = qmin + ln;
                    #pragma unroll
                    for (int nt = 0; nt < 4; ++nt)
                        #pragma unroll
                        for (int r = 0; r < 4; ++r)
                            if (k0 + nt*16 + quad*4 + r > qrow) sacc[hh][nt][r] = -1e30f;
                }
                #pragma unroll
                for (int nt = 0; nt < 4; ++nt) {
                    float p0 = __builtin_amdgcn_exp2f(fmaf(sacc[hh][nt][0], st2, dlv[nt][0]));
                    float p1 = __builtin_amdgcn_exp2f(fmaf(sacc[hh][nt][1], st2, dlv[nt][1]));
                    float p2 = __builtin_amdgcn_exp2f(fmaf(sacc[hh][nt][2], st2, dlv[nt][2]));
                    float p3 = __builtin_amdgcn_exp2f(fmaf(sacc[hh][nt][3], st2, dlv[nt][3]));
                    l_acc[hh] += (p0 + p1) + (p2 + p3);
                    pT[hh][nt] = (bf16x4){f2bs_rh(p0), f2bs_rh(p1), f2bs_rh(p2), f2bs_rh(p3)};
                }
            }

            // ---- O^T += V^T P^T  (16x16x16, P^T direct from registers) ----
            #pragma unroll
            for (int ntp = 0; ntp < 2; ++ntp)
                #pragma unroll
                for (int m16 = 0; m16 < 4; ++m16) {
                    bf16x8 vv = *(const bf16x8*)(Vc + (m16*2+ntp)*512 + lane*8);
                    bf16x4 v0 = (bf16x4){vv[0], vv[1], vv[2], vv[3]};
                    bf16x4 v1 = (bf16x4){vv[4], vv[5], vv[6], vv[7]};
                    #pragma unroll
                    for (int hh = 0; hh < 2; ++hh) {
                        oacc[hh][m16] = __builtin_amdgcn_mfma_f32_16x16x16bf16_1k(
                            v0, pT[hh][2*ntp+0], oacc[hh][m16], 0,0,0);
                        oacc[hh][m16] = __builtin_amdgcn_mfma_f32_16x16x16bf16_1k(
                            v1, pT[hh][2*ntp+1], oacc[hh][m16], 0,0,0);
                    }
                }
        }

        __syncthreads();   // staged t+1 complete + all reads of cur done
    }

    // ---- epilogue: reduce l across quads, normalize, store O (fp32) ----
    #pragma unroll
    for (int hh = 0; hh < 2; ++hh) {
        float lsum = l_acc[hh];
        lsum += __shfl_xor(lsum, 16, 64);
        lsum += __shfl_xor(lsum, 32, 64);
        const float inv = 1.0f / lsum;
        const int qrow = q0 + wv*32 + hh*16 + ln;
        float* orow = out + (((size_t)b*Lsz + qrow)*Hsz + h)*64;
        #pragma unroll
        for (int m16 = 0; m16 < 4; ++m16) {
            float4 o = {oacc[hh][m16][0]*inv, oacc[hh][m16][1]*inv,
                        oacc[hh][m16][2]*inv, oacc[hh][m16][3]*inv};
            *(float4*)(orow + m16*16 + quad*4) = o;
        }
    }
}

extern "C" void kernel_launch(void* const* d_in, const int* in_sizes, int n_in,
                              void* d_out, int out_size, void* d_ws, size_t ws_size,
                              hipStream_t stream) {
    (void)in_sizes; (void)n_in; (void)out_size; (void)ws_size;
    const float* q     = (const float*)d_in[0];
    const float* k     = (const float*)d_in[1];
    const float* v     = (const float*)d_in[2];
    const float* tau   = (const float*)d_in[3];
    const float* delta = (const float*)d_in[4];
    float* out = (float*)d_out;

    short* Kf = (short*)d_ws;                          // 8 MiB bf16 fragments
    short* Vf = (short*)d_ws + (size_t)(4*1024*1024);  // next 8 MiB

    prep_kv<<<dim3(Bsz*Hsz*32*2), dim3(256), 0, stream>>>(k, v, Kf, Vf);
    dsattn_main<<<dim3(Bsz*Hsz, 16), dim3(256), 0, stream>>>(q, Kf, Vf, tau, delta, out);
}

// Round 7
// 128.550 us; speedup vs baseline: 1.0484x; 1.0484x over previous
//
#include <hip/hip_runtime.h>
#include <hip/hip_bf16.h>

#define Bsz 4
#define Lsz 2048
#define Hsz 8

typedef __attribute__((ext_vector_type(8))) short bf16x8;
typedef __attribute__((ext_vector_type(4))) short bf16x4;
typedef __attribute__((ext_vector_type(4))) float f32x4;

__device__ __forceinline__ short f2bs(float f) {   // RNE, prep only
    union { float f; unsigned u; } v; v.f = f;
    unsigned r = v.u + 0x7FFFu + ((v.u >> 16) & 1u);
    return (short)(r >> 16);
}
__device__ __forceinline__ short f2bs_rh(float f) { // round-half-up, 2 ops
    return (short)((__float_as_uint(f) + 0x8000u) >> 16);
}

// async global->LDS, 16B per lane; LDS dest is wave-uniform base + lane*16
__device__ __forceinline__ void stage16(const short* g, short* l) {
    __builtin_amdgcn_global_load_lds(
        (const __attribute__((address_space(1))) unsigned int*)g,
        (__attribute__((address_space(3))) unsigned int*)l,
        16, 0, 0);
}

// ---------------- fused pre-pass: K and V -> bf16 MFMA fragments ----------------
// Per (bh, 64-key tile): 8 chunks x 1024 B, frag position = lane (conflict-free
// lane-linear LDS reads in main).
// K chunk c=nt*2+eh, lane(quad,ln): K[k0+nt*16+ln][eh*32+quad*8+j]  (A-op 16x16x32)
// V chunk c=m16*2+ntp, lane: 16B = [frag(nt=2ntp) | frag(nt=2ntp+1)], each
//   frag = V[k0+nt*16+quad*4+j][m16*16+ln] j=0..3                   (A-op 16x16x16)
__global__ __launch_bounds__(256) void prep_kv(
    const float* __restrict__ ksrc, const float* __restrict__ vsrc,
    short* __restrict__ Kf, short* __restrict__ Vf)
{
    __shared__ float Tl[64][65];
    const int raw = blockIdx.x;
    const int tid = threadIdx.x;
    const bool isK = raw < Bsz*Hsz*32;
    const int bid = isK ? raw : raw - Bsz*Hsz*32;
    const int tl = bid & 31, bh = bid >> 5;
    const int b = bh >> 3, h = bh & 7;

    // coalesced stage of the 64x64 fp32 tile
    const int row = tid >> 2, c0 = (tid & 3) * 16;
    const float* src = (isK ? ksrc : vsrc)
                     + (((size_t)b*Lsz + tl*64 + row)*Hsz + h)*64 + c0;
    *(float4*)&Tl[row][c0]      = *(const float4*)(src);
    *(float4*)&Tl[row][c0 + 4]  = *(const float4*)(src + 4);
    *(float4*)&Tl[row][c0 + 8]  = *(const float4*)(src + 8);
    *(float4*)&Tl[row][c0 + 12] = *(const float4*)(src + 12);
    __syncthreads();

    const int lane = tid & 63, ln = lane & 15, quad = lane >> 4;
    if (isK) {
        short* dst = Kf + (size_t)bid * 4096;
        #pragma unroll
        for (int cc = 0; cc < 2; ++cc) {
            const int c  = (tid >> 6)*2 + cc;
            const int nt = c >> 1, eh = c & 1;
            const float* rp = &Tl[nt*16 + ln][eh*32 + quad*8];
            bf16x8 o = {f2bs(rp[0]),f2bs(rp[1]),f2bs(rp[2]),f2bs(rp[3]),
                        f2bs(rp[4]),f2bs(rp[5]),f2bs(rp[6]),f2bs(rp[7])};
            *(bf16x8*)(dst + c*512 + lane*8) = o;
        }
    } else {
        short* dst = Vf + (size_t)bid * 4096;
        #pragma unroll
        for (int cc = 0; cc < 2; ++cc) {
            const int cp  = (tid >> 6)*2 + cc;
            const int m16 = cp >> 1, nt0 = (cp & 1)*2;
            const int d   = m16*16 + ln;
            const int s0  = nt0*16 + quad*4;
            bf16x8 o = {f2bs(Tl[s0+0][d]),  f2bs(Tl[s0+1][d]),
                        f2bs(Tl[s0+2][d]),  f2bs(Tl[s0+3][d]),
                        f2bs(Tl[s0+16][d]), f2bs(Tl[s0+17][d]),
                        f2bs(Tl[s0+18][d]), f2bs(Tl[s0+19][d])};
            *(bf16x8*)(dst + cp*512 + lane*8) = o;
        }
    }
}

// ---------------- main: S^T flash attention, zero-shuffle P->PV ----------------
// 256 thr = 4 waves; wave owns 16 q-rows; block = 64 q-rows; grid (32,32):
// 1024 blocks -> 4 blocks/CU all co-resident (16 waves/CU, 4/SIMD).
// S^T = mfma_16x16x32(kf, qf): C-layout key=quad*4+r, q=ln  ==  B-operand
// layout of mfma_16x16x16 -> P^T feeds O^T = V^T * P^T directly from regs.
// No-max softmax (|logit*log2e*scale*tau| <= ~13.5, l <= 2.4e7: fp32-safe).
__global__ __launch_bounds__(256, 4) void dsattn_main(
    const float* __restrict__ q,
    const short* __restrict__ Kf,
    const short* __restrict__ Vf,
    const float* __restrict__ tau,
    const float* __restrict__ delta,
    float* __restrict__ out)
{
    __shared__ __align__(16) short Kb[2][4096];   // 16 KB dbuf
    __shared__ __align__(16) short Vb[2][4096];   // 16 KB dbuf
    __shared__ float dls[Lsz];                    //  8 KB c2*delta[b][:]
    // total 40 KB -> 4 blocks/CU = 160 KB = full LDS

    const int tid  = threadIdx.x;
    const int wv   = tid >> 6;
    const int lane = tid & 63;
    const int ln   = lane & 15;
    const int quad = lane >> 4;

    const int bh = blockIdx.x;
    const int b  = bh >> 3, h = bh & 7;
    // co-resident y-group {y0, y0+8, y0+16, y0+24} -> qt {a,15-a,16+a,31-a}:
    // per-CU tile total = 66, balanced
    const int j  = blockIdx.y, aj = j & 7, gj = j >> 3;
    const int qt = (gj == 0) ? aj : (gj == 1) ? 15 - aj
                 : (gj == 2) ? 16 + aj : 31 - aj;
    const int q0 = qt * 64;
    const int T  = qt + 1;              // 64-key tiles

    const float c2  = 0.125f * 1.44269504f;   // scale * log2(e)
    const float st2 = c2 * tau[b];

    const short* kt = Kf + (size_t)bh * (32*4096);
    const short* vt = Vf + (size_t)bh * (32*4096);

    // stage c2*delta (256 thr x 8 floats)
    {
        const float* dsrc = delta + (size_t)b*Lsz + tid*8;
        float4 a = *(const float4*)(dsrc);
        float4 c = *(const float4*)(dsrc + 4);
        a.x*=c2; a.y*=c2; a.z*=c2; a.w*=c2;
        c.x*=c2; c.y*=c2; c.z*=c2; c.w*=c2;
        *(float4*)&dls[tid*8]     = a;
        *(float4*)&dls[tid*8 + 4] = c;
    }

    // stage tile 0 (16 chunks of 1KB; wave wv does chunks wv*4..+3)
    #pragma unroll
    for (int u = 0; u < 4; ++u) {
        const int c = wv*4 + u;
        const short* g = ((c < 8) ? kt : vt) + (c & 7)*512 + lane*8;
        short* l = ((c < 8) ? &Kb[0][0] : &Vb[0][0]) + (c & 7)*512;
        stage16(g, l);
    }

    // Q fragments (B-operand of 16x16x32), straight from fp32 global
    bf16x8 qf0, qf1;
    {
        const float* qrow = q + (((size_t)b*Lsz + q0 + wv*16 + ln)*Hsz + h)*64;
        float4 a0 = *(const float4*)(qrow + quad*8);
        float4 a1 = *(const float4*)(qrow + quad*8 + 4);
        float4 b0 = *(const float4*)(qrow + 32 + quad*8);
        float4 b1 = *(const float4*)(qrow + 32 + quad*8 + 4);
        qf0 = (bf16x8){f2bs(a0.x),f2bs(a0.y),f2bs(a0.z),f2bs(a0.w),
                       f2bs(a1.x),f2bs(a1.y),f2bs(a1.z),f2bs(a1.w)};
        qf1 = (bf16x8){f2bs(b0.x),f2bs(b0.y),f2bs(b0.z),f2bs(b0.w),
                       f2bs(b1.x),f2bs(b1.y),f2bs(b1.z),f2bs(b1.w)};
    }

    f32x4 oacc[4];
    #pragma unroll
    for (int m = 0; m < 4; ++m) oacc[m] = (f32x4){0.f,0.f,0.f,0.f};
    float l_acc = 0.f;

    __syncthreads();   // tile 0 + dls staged (barrier drains vmcnt)

    for (int t = 0; t < T; ++t) {
        const int cur = t & 1;
        if (t + 1 < T) {                       // stream tile t+1 into other buffer
            const int nb = cur ^ 1;
            #pragma unroll
            for (int u = 0; u < 4; ++u) {
                const int c = wv*4 + u;
                const short* g = ((c < 8) ? kt : vt)
                               + (size_t)(t+1)*4096 + (c & 7)*512 + lane*8;
                short* l = ((c < 8) ? &Kb[nb][0] : &Vb[nb][0]) + (c & 7)*512;
                stage16(g, l);
            }
        }

        const short* Kc = &Kb[cur][0];
        const short* Vc = &Vb[cur][0];
        const int k0 = t*64;

        // ---- S^T = K Q^T : lane holds [key=k0+nt*16+quad*4+r][q=q0+wv*16+ln] ----
        f32x4 sacc[4];
        #pragma unroll
        for (int nt = 0; nt < 4; ++nt) {
            bf16x8 kf0 = *(const bf16x8*)(Kc + (nt*2+0)*512 + lane*8);
            bf16x8 kf1 = *(const bf16x8*)(Kc + (nt*2+1)*512 + lane*8);
            f32x4 z = (f32x4){0.f,0.f,0.f,0.f};
            z = __builtin_amdgcn_mfma_f32_16x16x32_bf16(kf0, qf0, z, 0,0,0);
            sacc[nt] = __builtin_amdgcn_mfma_f32_16x16x32_bf16(kf1, qf1, z, 0,0,0);
        }

        // ---- delta (key-indexed, broadcast b128 reads) ----
        f32x4 dlv[4];
        #pragma unroll
        for (int nt = 0; nt < 4; ++nt)
            dlv[nt] = *(const f32x4*)&dls[k0 + nt*16 + quad*4];

        // ---- mask (diagonal tile only), exp2, pack P^T in registers ----
        if (t == qt) {
            const int qrow = q0 + wv*16 + ln;
            #pragma unroll
            for (int nt = 0; nt < 4; ++nt)
                #pragma unroll
                for (int r = 0; r < 4; ++r)
                    if (k0 + nt*16 + quad*4 + r > qrow) sacc[nt][r] = -1e30f;
        }
        bf16x4 pT[4];
        #pragma unroll
        for (int nt = 0; nt < 4; ++nt) {
            float p0 = __builtin_amdgcn_exp2f(fmaf(sacc[nt][0], st2, dlv[nt][0]));
            float p1 = __builtin_amdgcn_exp2f(fmaf(sacc[nt][1], st2, dlv[nt][1]));
            float p2 = __builtin_amdgcn_exp2f(fmaf(sacc[nt][2], st2, dlv[nt][2]));
            float p3 = __builtin_amdgcn_exp2f(fmaf(sacc[nt][3], st2, dlv[nt][3]));
            l_acc += (p0 + p1) + (p2 + p3);
            pT[nt] = (bf16x4){f2bs_rh(p0), f2bs_rh(p1), f2bs_rh(p2), f2bs_rh(p3)};
        }

        // ---- O^T += V^T P^T  (16x16x16, P^T direct from registers) ----
        #pragma unroll
        for (int ntp = 0; ntp < 2; ++ntp)
            #pragma unroll
            for (int m16 = 0; m16 < 4; ++m16) {
                bf16x8 vv = *(const bf16x8*)(Vc + (m16*2+ntp)*512 + lane*8);
                bf16x4 v0 = (bf16x4){vv[0], vv[1], vv[2], vv[3]};
                bf16x4 v1 = (bf16x4){vv[4], vv[5], vv[6], vv[7]};
                oacc[m16] = __builtin_amdgcn_mfma_f32_16x16x16bf16_1k(
                    v0, pT[2*ntp+0], oacc[m16], 0,0,0);
                oacc[m16] = __builtin_amdgcn_mfma_f32_16x16x16bf16_1k(
                    v1, pT[2*ntp+1], oacc[m16], 0,0,0);
            }

        __syncthreads();   // staged t+1 complete + all reads of cur done
    }

    // ---- epilogue: reduce l across quads, normalize, store O (fp32) ----
    float lsum = l_acc;
    lsum += __shfl_xor(lsum, 16, 64);
    lsum += __shfl_xor(lsum, 32, 64);
    const float inv = 1.0f / lsum;
    const int qrow = q0 + wv*16 + ln;
    float* orow = out + (((size_t)b*Lsz + qrow)*Hsz + h)*64;
    #pragma unroll
    for (int m16 = 0; m16 < 4; ++m16) {
        float4 o = {oacc[m16][0]*inv, oacc[m16][1]*inv,
                    oacc[m16][2]*inv, oacc[m16][3]*inv};
        *(float4*)(orow + m16*16 + quad*4) = o;
    }
}

extern "C" void kernel_launch(void* const* d_in, const int* in_sizes, int n_in,
                              void* d_out, int out_size, void* d_ws, size_t ws_size,
                              hipStream_t stream) {
    (void)in_sizes; (void)n_in; (void)out_size; (void)ws_size;
    const float* q     = (const float*)d_in[0];
    const float* k     = (const float*)d_in[1];
    const float* v     = (const float*)d_in[2];
    const float* tau   = (const float*)d_in[3];
    const float* delta = (const float*)d_in[4];
    float* out = (float*)d_out;

    short* Kf = (short*)d_ws;                          // 8 MiB bf16 fragments
    short* Vf = (short*)d_ws + (size_t)(4*1024*1024);  // next 8 MiB

    prep_kv<<<dim3(Bsz*Hsz*32*2), dim3(256), 0, stream>>>(k, v, Kf, Vf);
    dsattn_main<<<dim3(Bsz*Hsz, 32), dim3(256), 0, stream>>>(q, Kf, Vf, tau, delta, out);
}